// Round 5
// baseline (845.498 us; speedup 1.0000x reference)
//
#include <hip/hip_runtime.h>
#include <hip/hip_bf16.h>
#include <math.h>

#define DM 768
#define NH 12
#define HD 64
#define B_ 4
#define SQ_ 1024
#define SK_ 2048
#define QT 16
#define PSTR 40   // p-tile LDS row stride (bf16 elems): 80 B, 16B-aligned, bank-clean

typedef __bf16 bf16x8 __attribute__((ext_vector_type(8)));
typedef __bf16 bf16x4 __attribute__((ext_vector_type(4)));
typedef float f32x4 __attribute__((ext_vector_type(4)));

static __device__ __forceinline__ f32x4 mfma16(bf16x8 a, bf16x8 b, f32x4 c) {
    return __builtin_amdgcn_mfma_f32_16x16x32_bf16(a, b, c, 0, 0, 0);
}

// async global->LDS, 16 B per lane (dest: wave-uniform base + lane*16)
static __device__ __forceinline__ void glds16(const void* g, void* l) {
    __builtin_amdgcn_global_load_lds(
        (const __attribute__((address_space(1))) void*)g,
        (__attribute__((address_space(3))) void*)l, 16, 0, 0);
}

// ---------------- block reductions (256 threads, 4 waves of 64) ----------------
__device__ __forceinline__ float blksum(float v, float* rb, int tid) {
#pragma unroll
    for (int off = 32; off; off >>= 1) v += __shfl_down(v, off, 64);
    if ((tid & 63) == 0) rb[tid >> 6] = v;
    __syncthreads();
    if (tid == 0) rb[4] = rb[0] + rb[1] + rb[2] + rb[3];
    __syncthreads();
    return rb[4];
}

// ---------------- W transpose + cast: Wt[n][k] bf16 from W[k][n] fp32 ----------
__global__ __launch_bounds__(256)
void transpose_cast(const float* __restrict__ W0, const float* __restrict__ W1,
                    const float* __restrict__ W2,
                    __hip_bfloat16* __restrict__ T0, __hip_bfloat16* __restrict__ T1,
                    __hip_bfloat16* __restrict__ T2)
{
    __shared__ float Ls[64][68];
    const int z = blockIdx.z;
    const float* W = (z == 0) ? W0 : (z == 1) ? W1 : W2;
    __hip_bfloat16* T = (z == 0) ? T0 : (z == 1) ? T1 : T2;
    const int k0 = blockIdx.y * 64, n0 = blockIdx.x * 64;
    const int tid = threadIdx.x;
    const int kl = tid >> 4, n4 = (tid & 15) * 4;
#pragma unroll
    for (int p = 0; p < 4; ++p) {
        float4 v = *(const float4*)&W[(size_t)(k0 + kl + p * 16) * DM + n0 + n4];
        *(float4*)&Ls[kl + p * 16][n4] = v;
    }
    __syncthreads();
    const int nl = tid >> 2, kq = (tid & 3) * 16;
    __hip_bfloat16 tmp[16];
#pragma unroll
    for (int i = 0; i < 16; ++i) tmp[i] = __float2bfloat16(Ls[kq + i][nl]);
    *(bf16x8*)&T[(size_t)(n0 + nl) * DM + k0 + kq]     = *(bf16x8*)&tmp[0];
    *(bf16x8*)&T[(size_t)(n0 + nl) * DM + k0 + kq + 8] = *(bf16x8*)&tmp[8];
}

// ---------------- fp32 -> (hi, lo) bf16 split, streaming ----------------------
__global__ __launch_bounds__(256)
void split_bf16(const float* __restrict__ X, __hip_bfloat16* __restrict__ Xh,
                __hip_bfloat16* __restrict__ Xl, int n4)
{
    const int i = blockIdx.x * 256 + threadIdx.x;
    if (i >= n4) return;
    float4 v = ((const float4*)X)[i];
    float xs[4] = {v.x, v.y, v.z, v.w};
    bf16x4 h, l;
#pragma unroll
    for (int e = 0; e < 4; ++e) {
        const __bf16 hh = (__bf16)xs[e];
        h[e] = hh;
        l[e] = (__bf16)(xs[e] - (float)hh);
    }
    *(bf16x4*)&Xh[(size_t)i * 4] = h;
    *(bf16x4*)&Xl[(size_t)i * 4] = l;
}

// ---------------- split-bf16 MFMA GEMM (m97 structure) -------------------------
// C[M x 768] = (Ahg + Alg)[M x 768] @ Wt^T, Wt[n][k] bf16.
// 128x128 tile, BK=32, 256 thr (4 waves 2x2), global_load_lds(16B) -> linear
// [128][32] LDS, double-buffered, ONE barrier per K-chunk.
// MODE 0: bf16 head-split; MODE 1: fp32 + bias + resid; MODE 2: bf16 transposed.
template <int MODE>
__global__ __launch_bounds__(256)
void gemm_mfma(const __hip_bfloat16* __restrict__ Ahg, const __hip_bfloat16* __restrict__ Alg,
               const __hip_bfloat16* __restrict__ Wt,
               float* __restrict__ outf, __hip_bfloat16* __restrict__ outb, int S,
               const float* __restrict__ bias, const float* __restrict__ resid)
{
    __shared__ __align__(16) __hip_bfloat16 sAh[2][128][32];
    __shared__ __align__(16) __hip_bfloat16 sAl[2][128][32];
    __shared__ __align__(16) __hip_bfloat16 sWs[2][128][32];

    const int tid  = threadIdx.x;
    const int lane = tid & 63;
    const int w    = tid >> 6;
    const int l16  = lane & 15;
    const int lq   = lane >> 4;
    const int wr   = w >> 1, wc = w & 1;

    const int bn = blockIdx.x % (DM / 128);
    const int bm = blockIdx.x / (DM / 128);
    const int row0 = bm * 128, col0 = bn * 128;

    const int sr  = tid >> 2;          // staging row 0..63 (and +64)
    const int sc8 = (tid & 3) * 8;     // staging col block

    char* const dA = (char*)&sAh[0][0][0] + tid * 16;
    char* const dL = (char*)&sAl[0][0][0] + tid * 16;
    char* const dW = (char*)&sWs[0][0][0] + tid * 16;

    auto issue = [&](int buf, int k0) {
        const size_t ao = (size_t)(row0 + sr) * DM + k0 + sc8;
        const size_t wo = (size_t)(col0 + sr) * DM + k0 + sc8;
        const int bofs = buf * 8192;
        glds16(Ahg + ao,                 dA + bofs);
        glds16(Ahg + ao + (size_t)64*DM, dA + bofs + 4096);
        glds16(Alg + ao,                 dL + bofs);
        glds16(Alg + ao + (size_t)64*DM, dL + bofs + 4096);
        glds16(Wt  + wo,                 dW + bofs);
        glds16(Wt  + wo + (size_t)64*DM, dW + bofs + 4096);
    };

    f32x4 acc[4][4] = {};
    issue(0, 0);
    int cur = 0;
    for (int c = 0; c < DM / 32; ++c) {
        __syncthreads();                       // buf[cur] landed; readers of cur^1 done
        if (c + 1 < DM / 32) issue(cur ^ 1, (c + 1) * 32);

        bf16x8 bfr[4];
#pragma unroll
        for (int j = 0; j < 4; ++j)
            bfr[j] = *(const bf16x8*)&sWs[cur][wc * 64 + j * 16 + l16][lq * 8];
#pragma unroll
        for (int i = 0; i < 4; ++i) {
            const bf16x8 ah = *(const bf16x8*)&sAh[cur][wr * 64 + i * 16 + l16][lq * 8];
            const bf16x8 al = *(const bf16x8*)&sAl[cur][wr * 64 + i * 16 + l16][lq * 8];
#pragma unroll
            for (int j = 0; j < 4; ++j) {
                acc[i][j] = mfma16(ah, bfr[j], acc[i][j]);
                acc[i][j] = mfma16(al, bfr[j], acc[i][j]);
            }
        }
        cur ^= 1;
    }

    // ---- epilogue: row = row0+wr*64+i*16+lq*4+rr, col = col0+wc*64+j*16+l16 ----
    int b_blk = 0, s_base = 0;
    if (MODE != 1) {
        b_blk  = row0 / S;
        s_base = row0 - b_blk * S + wr * 64;
    }
#pragma unroll
    for (int i = 0; i < 4; ++i) {
#pragma unroll
        for (int j = 0; j < 4; ++j) {
#pragma unroll
            for (int rr = 0; rr < 4; ++rr) {
                const int cc = col0 + wc * 64 + j * 16 + l16;
                if (MODE == 1) {
                    const int r = row0 + wr * 64 + i * 16 + lq * 4 + rr;
                    outf[(size_t)r * DM + cc] =
                        acc[i][j][rr] + bias[cc] + resid[(size_t)r * DM + cc];
                } else {
                    const int s  = s_base + i * 16 + lq * 4 + rr;
                    const int h  = cc >> 6, hd = cc & 63;
                    if (MODE == 0)
                        outb[(((size_t)b_blk * NH + h) * S + s) * HD + hd] =
                            __float2bfloat16(acc[i][j][rr]);
                    else
                        outb[(((size_t)b_blk * NH + h) * HD + hd) * S + s] =
                            __float2bfloat16(acc[i][j][rr]);
                }
            }
        }
    }
}

// ---------------- recompute-flash attention: 16 q-rows x full SK ---------------
// Sweep 1: QK^T + exp, row-sums in registers (no p storage).
// Sweep 2: recompute QK^T + exp, write normalized fp32 attn straight from accs,
// stage per-wave 16x32 bf16 p-tile (stride PSTR=40) to feed PV MFMA.
// LDS ~5.4 KB -> ~5 blocks/CU. Wave w: k-strip [512w,512w+512), PV d-tile [16w,16w+16).
__global__ __launch_bounds__(256)
void attn_flash(const __hip_bfloat16* __restrict__ Qb,
                const __hip_bfloat16* __restrict__ Kb,
                const __hip_bfloat16* __restrict__ Vt,
                const int* __restrict__ mask, const float* __restrict__ temp,
                float* __restrict__ attn, float* __restrict__ ctx)
{
    __shared__ float wsum[4][16];
    __shared__ __align__(16) __hip_bfloat16 ptile[4][16][PSTR];

    const int tid  = threadIdx.x;
    const int lane = tid & 63;
    const int w    = tid >> 6;
    const int l16  = lane & 15;
    const int lq   = lane >> 4;

    const int nqt = SQ_ / QT;                  // 64
    const int qt  = blockIdx.x % nqt;
    const int h   = (blockIdx.x / nqt) % NH;
    const int b   = blockIdx.x / (nqt * NH);
    const int q0  = qt * QT;

    const float factor = 0.125f / temp[0];

    const __hip_bfloat16* Qbase = Qb + (((size_t)b * NH + h) * SQ_ + q0) * HD;
    const __hip_bfloat16* Kbase = Kb + ((size_t)b * NH + h) * SK_ * HD;
    const __hip_bfloat16* Vbase = Vt + ((size_t)b * NH + h) * HD * SK_;
    const int* mbase = mask + b * SK_;

    const bf16x8 a0 = *(const bf16x8*)&Qbase[(size_t)l16 * HD + lq * 8];
    const bf16x8 a1 = *(const bf16x8*)&Qbase[(size_t)l16 * HD + 32 + lq * 8];

    const int kw = w * 512;

    // ---- sweep 1: row sums only ----
    float ssum[4] = {0.f, 0.f, 0.f, 0.f};
    for (int t = 0; t < 32; ++t) {
        const int k0 = kw + t * 16;
        const __hip_bfloat16* Krow = &Kbase[(size_t)(k0 + l16) * HD];
        bf16x8 b0 = *(const bf16x8*)&Krow[lq * 8];
        bf16x8 b1 = *(const bf16x8*)&Krow[32 + lq * 8];
        f32x4 acc = {};
        acc = mfma16(a0, b0, acc);
        acc = mfma16(a1, b1, acc);
        const bool live = mbase[k0 + l16] != 0;
#pragma unroll
        for (int r = 0; r < 4; ++r)
            ssum[r] += live ? __expf(acc[r] * factor) : 0.f;
    }
    // reduce over the 16 lanes of each lq group (cols of this wave's strip)
#pragma unroll
    for (int r = 0; r < 4; ++r)
#pragma unroll
        for (int off = 1; off < 16; off <<= 1)
            ssum[r] += __shfl_xor(ssum[r], off, 64);
    if (l16 == 0) {
#pragma unroll
        for (int r = 0; r < 4; ++r) wsum[w][lq * 4 + r] = ssum[r];
    }
    __syncthreads();
    float inv[4];
#pragma unroll
    for (int r = 0; r < 4; ++r) {
        const int row = lq * 4 + r;
        inv[r] = 1.f / (wsum[0][row] + wsum[1][row] + wsum[2][row] + wsum[3][row]);
    }

    // ---- sweep 2: attn write + PV ----
    f32x4 pv = {};
    float* abase = attn + ((size_t)((b * NH + h) * SQ_) + q0) * SK_;
    for (int t = 0; t < 32; ++t) {
        const int k0 = kw + t * 16;
        const __hip_bfloat16* Krow = &Kbase[(size_t)(k0 + l16) * HD];
        bf16x8 b0 = *(const bf16x8*)&Krow[lq * 8];
        bf16x8 b1 = *(const bf16x8*)&Krow[32 + lq * 8];
        f32x4 acc = {};
        acc = mfma16(a0, b0, acc);
        acc = mfma16(a1, b1, acc);
        const bool live = mbase[k0 + l16] != 0;
        const int colb = (t & 1) * 16 + l16;
#pragma unroll
        for (int r = 0; r < 4; ++r) {
            const float e = live ? __expf(acc[r] * factor) * inv[r] : 0.f;
            abase[(size_t)(lq * 4 + r) * SK_ + k0 + l16] = e;      // normalized fp32
            ptile[w][lq * 4 + r][colb] = __float2bfloat16(e);      // normalized bf16
        }
        if (t & 1) {
            const bf16x8 ap = *(const bf16x8*)&ptile[w][l16][lq * 8];
            const bf16x8 bp = *(const bf16x8*)&Vbase[(size_t)(w * 16 + l16) * SK_
                                                     + (kw + (t - 1) * 16) + lq * 8];
            pv = mfma16(ap, bp, pv);
        }
    }
#pragma unroll
    for (int r = 0; r < 4; ++r) {
        const int row = lq * 4 + r;
        ctx[((size_t)(b * SQ_) + q0 + row) * DM + h * HD + w * 16 + l16] = pv[r];
    }
}

// ---------------- in-place LayerNorm on d_out rows ----------------
__global__ __launch_bounds__(256)
void ln_kernel(float* __restrict__ x, const float* __restrict__ gamma,
               const float* __restrict__ beta)
{
    __shared__ float rb[8];
    const int row = blockIdx.x;
    const int tid = threadIdx.x;
    float v[3];
    float s = 0.f;
#pragma unroll
    for (int i = 0; i < 3; ++i) {
        v[i] = x[(size_t)row * DM + tid + i * 256];
        s += v[i];
    }
    s = blksum(s, rb, tid);
    const float mean = s * (1.0f / DM);
    float s2 = 0.f;
#pragma unroll
    for (int i = 0; i < 3; ++i) {
        const float d = v[i] - mean;
        s2 += d * d;
    }
    s2 = blksum(s2, rb, tid);
    const float rstd = rsqrtf(s2 * (1.0f / DM) + 1e-5f);
#pragma unroll
    for (int i = 0; i < 3; ++i) {
        const int c = tid + i * 256;
        x[(size_t)row * DM + c] = gamma[c] * (v[i] - mean) * rstd + beta[c];
    }
}

extern "C" void kernel_launch(void* const* d_in, const int* in_sizes, int n_in,
                              void* d_out, int out_size, void* d_ws, size_t ws_size,
                              hipStream_t stream)
{
    const float* query = (const float*)d_in[0];
    const float* key   = (const float*)d_in[1];
    const float* value = (const float*)d_in[2];
    const int*   mask  = (const int*)d_in[3];
    const float* Wq    = (const float*)d_in[4];
    const float* Wk    = (const float*)d_in[5];
    const float* Wv    = (const float*)d_in[6];
    const float* Wo    = (const float*)d_in[7];
    const float* bo    = (const float*)d_in[8];
    const float* gamma = (const float*)d_in[9];
    const float* beta  = (const float*)d_in[10];
    const float* temp  = (const float*)d_in[11];

    float* out  = (float*)d_out;                          // [B,SQ,DM]
    float* attn = out + (size_t)B_ * SQ_ * DM;            // [B,NH,SQ,SK] fp32

    __hip_bfloat16* Qb = (__hip_bfloat16*)d_ws;           // [B,NH,SQ,HD]   6.3 MB
    __hip_bfloat16* Kb = Qb + (size_t)B_ * NH * SQ_ * HD; // [B,NH,SK,HD]  12.6 MB
    __hip_bfloat16* Vt = Kb + (size_t)B_ * NH * SK_ * HD; // [B,NH,HD,SK]  12.6 MB
    float* ctx = (float*)(Vt + (size_t)B_ * NH * SK_ * HD); // [B,SQ,DM]   12.6 MB
    // split scratch (sized for the largest matrix: 8192x768), reused per GEMM
    __hip_bfloat16* Sh = (__hip_bfloat16*)(ctx + (size_t)B_ * SQ_ * DM);  // 12.6 MB
    __hip_bfloat16* Sl = Sh + (size_t)B_ * SK_ * DM;                      // 12.6 MB

    // weight transposes parked in not-yet-written regions:
    //   Wqt/Wkt/Wvt in ctx area (ctx produced later by attn); Wot in Qb (dead after attn)
    __hip_bfloat16* Wqt = (__hip_bfloat16*)ctx;
    __hip_bfloat16* Wkt = Wqt + (size_t)DM * DM;
    __hip_bfloat16* Wvt = Wkt + (size_t)DM * DM;
    __hip_bfloat16* Wot = Qb;

    const int n4_q = B_ * SQ_ * DM / 4;   // 786432
    const int n4_k = B_ * SK_ * DM / 4;   // 1572864

    dim3 blk(256);
    hipLaunchKernelGGL(transpose_cast, dim3(12, 12, 3), blk, 0, stream,
                       Wq, Wk, Wv, Wqt, Wkt, Wvt);

    hipLaunchKernelGGL(split_bf16, dim3(n4_q / 256), blk, 0, stream, query, Sh, Sl, n4_q);
    hipLaunchKernelGGL((gemm_mfma<0>), dim3((B_ * SQ_ / 128) * (DM / 128)), blk, 0, stream,
                       Sh, Sl, Wqt, (float*)nullptr, Qb, SQ_, (const float*)nullptr, (const float*)nullptr);

    hipLaunchKernelGGL(split_bf16, dim3(n4_k / 256), blk, 0, stream, key, Sh, Sl, n4_k);
    hipLaunchKernelGGL((gemm_mfma<0>), dim3((B_ * SK_ / 128) * (DM / 128)), blk, 0, stream,
                       Sh, Sl, Wkt, (float*)nullptr, Kb, SK_, (const float*)nullptr, (const float*)nullptr);

    hipLaunchKernelGGL(split_bf16, dim3(n4_k / 256), blk, 0, stream, value, Sh, Sl, n4_k);
    hipLaunchKernelGGL((gemm_mfma<2>), dim3((B_ * SK_ / 128) * (DM / 128)), blk, 0, stream,
                       Sh, Sl, Wvt, (float*)nullptr, Vt, SK_, (const float*)nullptr, (const float*)nullptr);

    hipLaunchKernelGGL(attn_flash, dim3(B_ * NH * (SQ_ / QT)), blk, 0, stream,
                       Qb, Kb, Vt, mask, temp, attn, ctx);

    hipLaunchKernelGGL(transpose_cast, dim3(12, 12, 1), blk, 0, stream,
                       Wo, Wo, Wo, Wot, Wot, Wot);
    hipLaunchKernelGGL(split_bf16, dim3(n4_q / 256), blk, 0, stream, ctx, Sh, Sl, n4_q);
    hipLaunchKernelGGL((gemm_mfma<1>), dim3((B_ * SQ_ / 128) * (DM / 128)), blk, 0, stream,
                       Sh, Sl, Wot, out, (__hip_bfloat16*)nullptr, SQ_, bo, query);

    hipLaunchKernelGGL(ln_kernel, dim3(B_ * SQ_), blk, 0, stream, out, gamma, beta);
}

// Round 6
// 806.842 us; speedup vs baseline: 1.0479x; 1.0479x over previous
//
#include <hip/hip_runtime.h>
#include <hip/hip_bf16.h>
#include <math.h>

#define DM 768
#define NH 12
#define HD 64
#define B_ 4
#define SQ_ 1024
#define SK_ 2048
#define QT 16
#define PSTR 40   // p-tile LDS row stride (bf16 elems): 80 B, 16B-aligned, bank-clean

typedef __bf16 bf16x8 __attribute__((ext_vector_type(8)));
typedef __bf16 bf16x4 __attribute__((ext_vector_type(4)));
typedef float f32x4 __attribute__((ext_vector_type(4)));

static __device__ __forceinline__ f32x4 mfma16(bf16x8 a, bf16x8 b, f32x4 c) {
    return __builtin_amdgcn_mfma_f32_16x16x32_bf16(a, b, c, 0, 0, 0);
}

// async global->LDS, 16 B per lane (dest: wave-uniform base + lane*16)
static __device__ __forceinline__ void glds16(const void* g, void* l) {
    __builtin_amdgcn_global_load_lds(
        (const __attribute__((address_space(1))) void*)g,
        (__attribute__((address_space(3))) void*)l, 16, 0, 0);
}

// ---------------- block reductions (256 threads, 4 waves of 64) ----------------
__device__ __forceinline__ float blksum(float v, float* rb, int tid) {
#pragma unroll
    for (int off = 32; off; off >>= 1) v += __shfl_down(v, off, 64);
    if ((tid & 63) == 0) rb[tid >> 6] = v;
    __syncthreads();
    if (tid == 0) rb[4] = rb[0] + rb[1] + rb[2] + rb[3];
    __syncthreads();
    return rb[4];
}

// ---------------- W transpose + cast: Wt[n][k] bf16 from W[k][n] fp32 ----------
__global__ __launch_bounds__(256)
void transpose_cast(const float* __restrict__ W0, const float* __restrict__ W1,
                    const float* __restrict__ W2,
                    __hip_bfloat16* __restrict__ T0, __hip_bfloat16* __restrict__ T1,
                    __hip_bfloat16* __restrict__ T2)
{
    __shared__ float Ls[64][68];
    const int z = blockIdx.z;
    const float* W = (z == 0) ? W0 : (z == 1) ? W1 : W2;
    __hip_bfloat16* T = (z == 0) ? T0 : (z == 1) ? T1 : T2;
    const int k0 = blockIdx.y * 64, n0 = blockIdx.x * 64;
    const int tid = threadIdx.x;
    const int kl = tid >> 4, n4 = (tid & 15) * 4;
#pragma unroll
    for (int p = 0; p < 4; ++p) {
        float4 v = *(const float4*)&W[(size_t)(k0 + kl + p * 16) * DM + n0 + n4];
        *(float4*)&Ls[kl + p * 16][n4] = v;
    }
    __syncthreads();
    const int nl = tid >> 2, kq = (tid & 3) * 16;
    __hip_bfloat16 tmp[16];
#pragma unroll
    for (int i = 0; i < 16; ++i) tmp[i] = __float2bfloat16(Ls[kq + i][nl]);
    *(bf16x8*)&T[(size_t)(n0 + nl) * DM + k0 + kq]     = *(bf16x8*)&tmp[0];
    *(bf16x8*)&T[(size_t)(n0 + nl) * DM + k0 + kq + 8] = *(bf16x8*)&tmp[8];
}

// ---------------- fp32 -> (hi, lo) bf16 split ---------------------------------
__device__ __forceinline__ void split_body(const float* __restrict__ X,
                                           __hip_bfloat16* __restrict__ Xh,
                                           __hip_bfloat16* __restrict__ Xl, int i)
{
    float4 v = ((const float4*)X)[i];
    float xs[4] = {v.x, v.y, v.z, v.w};
    bf16x4 h, l;
#pragma unroll
    for (int e = 0; e < 4; ++e) {
        const __bf16 hh = (__bf16)xs[e];
        h[e] = hh;
        l[e] = (__bf16)(xs[e] - (float)hh);
    }
    *(bf16x4*)&Xh[(size_t)i * 4] = h;
    *(bf16x4*)&Xl[(size_t)i * 4] = l;
}

__global__ __launch_bounds__(256)
void split_bf16(const float* __restrict__ X, __hip_bfloat16* __restrict__ Xh,
                __hip_bfloat16* __restrict__ Xl)
{
    split_body(X, Xh, Xl, blockIdx.x * 256 + threadIdx.x);
}

// fused q/k/v split: blocks [0,3072) q, [3072,9216) k, [9216,15360) v
__global__ __launch_bounds__(256)
void split3_bf16(const float* __restrict__ q, const float* __restrict__ k,
                 const float* __restrict__ v,
                 __hip_bfloat16* __restrict__ qh, __hip_bfloat16* __restrict__ ql,
                 __hip_bfloat16* __restrict__ kh, __hip_bfloat16* __restrict__ kl,
                 __hip_bfloat16* __restrict__ vh, __hip_bfloat16* __restrict__ vl)
{
    const int b = blockIdx.x;
    const float* X; __hip_bfloat16 *H, *L; int base;
    if (b < 3072)      { X = q; H = qh; L = ql; base = b; }
    else if (b < 9216) { X = k; H = kh; L = kl; base = b - 3072; }
    else               { X = v; H = vh; L = vl; base = b - 9216; }
    split_body(X, H, L, base * 256 + threadIdx.x);
}

// ---------------- split-bf16 MFMA GEMM body (m97 structure) --------------------
// C[M x 768] = (Ahg + Alg) @ Wt^T, Wt[n][k] bf16. BM x 128 tile, BK=32,
// 256 thr (4 waves 2x2, wave tile BM/2 x 64), global_load_lds(16B) -> linear
// LDS, double-buffered, one barrier per K-chunk.
// mode 0: bf16 head-split; mode 1: fp32 + bias + resid; mode 2: bf16 transposed.
template <int BM>
__device__ __forceinline__ void gemm_body(
    const __hip_bfloat16* __restrict__ Ahg, const __hip_bfloat16* __restrict__ Alg,
    const __hip_bfloat16* __restrict__ Wt,
    float* __restrict__ outf, __hip_bfloat16* __restrict__ outb, int S,
    const float* __restrict__ bias, const float* __restrict__ resid,
    int lbid, int mode)
{
    constexpr int NI = BM / 32;            // row frags per wave
    constexpr int ABYTES = BM * 64;        // bytes per A buffer
    __shared__ __align__(16) __hip_bfloat16 sAh[2][BM][32];
    __shared__ __align__(16) __hip_bfloat16 sAl[2][BM][32];
    __shared__ __align__(16) __hip_bfloat16 sWs[2][128][32];

    const int tid  = threadIdx.x;
    const int lane = tid & 63;
    const int w    = tid >> 6;
    const int l16  = lane & 15;
    const int lq   = lane >> 4;
    const int wr   = w >> 1, wc = w & 1;

    const int bn = lbid % (DM / 128);
    const int bm = lbid / (DM / 128);
    const int row0 = bm * BM, col0 = bn * 128;

    const int sr  = tid >> 2;              // staging row 0..63
    const int sc8 = (tid & 3) * 8;

    char* const dA = (char*)&sAh[0][0][0] + tid * 16;
    char* const dL = (char*)&sAl[0][0][0] + tid * 16;
    char* const dW = (char*)&sWs[0][0][0] + tid * 16;

    auto issue = [&](int buf, int k0) {
        const size_t ao = (size_t)(row0 + sr) * DM + k0 + sc8;
        const size_t wo = (size_t)(col0 + sr) * DM + k0 + sc8;
        glds16(Ahg + ao, dA + buf * ABYTES);
        glds16(Alg + ao, dL + buf * ABYTES);
        if constexpr (BM == 128) {
            glds16(Ahg + ao + (size_t)64 * DM, dA + buf * ABYTES + 4096);
            glds16(Alg + ao + (size_t)64 * DM, dL + buf * ABYTES + 4096);
        }
        glds16(Wt + wo,                 dW + buf * 8192);
        glds16(Wt + wo + (size_t)64*DM, dW + buf * 8192 + 4096);
    };

    f32x4 acc[NI][4] = {};
    issue(0, 0);
    int cur = 0;
    for (int c = 0; c < DM / 32; ++c) {
        __syncthreads();                   // buf[cur] landed; readers of cur^1 done
        if (c + 1 < DM / 32) issue(cur ^ 1, (c + 1) * 32);

        bf16x8 bfr[4];
#pragma unroll
        for (int j = 0; j < 4; ++j)
            bfr[j] = *(const bf16x8*)&sWs[cur][wc * 64 + j * 16 + l16][lq * 8];
#pragma unroll
        for (int i = 0; i < NI; ++i) {
            const bf16x8 ah = *(const bf16x8*)&sAh[cur][wr * (BM/2) + i * 16 + l16][lq * 8];
            const bf16x8 al = *(const bf16x8*)&sAl[cur][wr * (BM/2) + i * 16 + l16][lq * 8];
#pragma unroll
            for (int j = 0; j < 4; ++j) {
                acc[i][j] = mfma16(ah, bfr[j], acc[i][j]);
                acc[i][j] = mfma16(al, bfr[j], acc[i][j]);
            }
        }
        cur ^= 1;
    }

    // ---- epilogue: row = row0+wr*(BM/2)+i*16+lq*4+rr, col = col0+wc*64+j*16+l16
    int b_blk = 0, s_base = 0;
    if (mode != 1) {
        b_blk  = row0 / S;
        s_base = row0 - b_blk * S + wr * (BM / 2);
    }
#pragma unroll
    for (int i = 0; i < NI; ++i) {
#pragma unroll
        for (int j = 0; j < 4; ++j) {
#pragma unroll
            for (int rr = 0; rr < 4; ++rr) {
                const int cc = col0 + wc * 64 + j * 16 + l16;
                if (mode == 1) {
                    const int r = row0 + wr * (BM/2) + i * 16 + lq * 4 + rr;
                    outf[(size_t)r * DM + cc] =
                        acc[i][j][rr] + bias[cc] + resid[(size_t)r * DM + cc];
                } else {
                    const int s  = s_base + i * 16 + lq * 4 + rr;
                    const int h  = cc >> 6, hd = cc & 63;
                    if (mode == 0)
                        outb[(((size_t)b_blk * NH + h) * S + s) * HD + hd] =
                            __float2bfloat16(acc[i][j][rr]);
                    else
                        outb[(((size_t)b_blk * NH + h) * HD + hd) * S + s] =
                            __float2bfloat16(acc[i][j][rr]);
                }
            }
        }
    }
}

// fused QKV projection: blocks [0,192) Q, [192,576) K, [576,960) V
__global__ __launch_bounds__(256)
void gemm_qkv(const __hip_bfloat16* __restrict__ qh, const __hip_bfloat16* __restrict__ ql,
              const __hip_bfloat16* __restrict__ kh, const __hip_bfloat16* __restrict__ kl,
              const __hip_bfloat16* __restrict__ vh, const __hip_bfloat16* __restrict__ vl,
              const __hip_bfloat16* __restrict__ Wqt, const __hip_bfloat16* __restrict__ Wkt,
              const __hip_bfloat16* __restrict__ Wvt,
              __hip_bfloat16* __restrict__ Qb, __hip_bfloat16* __restrict__ Kb,
              __hip_bfloat16* __restrict__ Vt)
{
    const int bid = blockIdx.x;
    if (bid < 192)
        gemm_body<128>(qh, ql, Wqt, nullptr, Qb, SQ_, nullptr, nullptr, bid, 0);
    else if (bid < 576)
        gemm_body<128>(kh, kl, Wkt, nullptr, Kb, SK_, nullptr, nullptr, bid - 192, 0);
    else
        gemm_body<128>(vh, vl, Wvt, nullptr, Vt, SK_, nullptr, nullptr, bid - 576, 2);
}

// O projection: BM=64 (384 blocks), fp32 out + bias + residual
__global__ __launch_bounds__(256)
void gemm_o(const __hip_bfloat16* __restrict__ ah, const __hip_bfloat16* __restrict__ al,
            const __hip_bfloat16* __restrict__ Wot, float* __restrict__ outf,
            const float* __restrict__ bias, const float* __restrict__ resid)
{
    gemm_body<64>(ah, al, Wot, outf, nullptr, SQ_, bias, resid, blockIdx.x, 1);
}

// ---------------- recompute-flash attention: 16 q-rows x full SK ---------------
// Sweep 1: QK^T + exp, row-sums in registers (no p storage).
// Sweep 2: recompute QK^T + exp, write normalized fp32 attn straight from accs,
// stage per-wave 16x32 bf16 p-tile (stride PSTR=40) to feed PV MFMA.
// LDS ~5.4 KB. Wave w: k-strip [512w,512w+512), PV d-tile [16w,16w+16).
__global__ __launch_bounds__(256)
void attn_flash(const __hip_bfloat16* __restrict__ Qb,
                const __hip_bfloat16* __restrict__ Kb,
                const __hip_bfloat16* __restrict__ Vt,
                const int* __restrict__ mask, const float* __restrict__ temp,
                float* __restrict__ attn, float* __restrict__ ctx)
{
    __shared__ float wsum[4][16];
    __shared__ __align__(16) __hip_bfloat16 ptile[4][16][PSTR];

    const int tid  = threadIdx.x;
    const int lane = tid & 63;
    const int w    = tid >> 6;
    const int l16  = lane & 15;
    const int lq   = lane >> 4;

    const int nqt = SQ_ / QT;                  // 64
    const int qt  = blockIdx.x % nqt;
    const int h   = (blockIdx.x / nqt) % NH;
    const int b   = blockIdx.x / (nqt * NH);
    const int q0  = qt * QT;

    const float factor = 0.125f / temp[0];

    const __hip_bfloat16* Qbase = Qb + (((size_t)b * NH + h) * SQ_ + q0) * HD;
    const __hip_bfloat16* Kbase = Kb + ((size_t)b * NH + h) * SK_ * HD;
    const __hip_bfloat16* Vbase = Vt + ((size_t)b * NH + h) * HD * SK_;
    const int* mbase = mask + b * SK_;

    const bf16x8 a0 = *(const bf16x8*)&Qbase[(size_t)l16 * HD + lq * 8];
    const bf16x8 a1 = *(const bf16x8*)&Qbase[(size_t)l16 * HD + 32 + lq * 8];

    const int kw = w * 512;

    // ---- sweep 1: row sums only ----
    float ssum[4] = {0.f, 0.f, 0.f, 0.f};
    for (int t = 0; t < 32; ++t) {
        const int k0 = kw + t * 16;
        const __hip_bfloat16* Krow = &Kbase[(size_t)(k0 + l16) * HD];
        bf16x8 b0 = *(const bf16x8*)&Krow[lq * 8];
        bf16x8 b1 = *(const bf16x8*)&Krow[32 + lq * 8];
        f32x4 acc = {};
        acc = mfma16(a0, b0, acc);
        acc = mfma16(a1, b1, acc);
        const bool live = mbase[k0 + l16] != 0;
#pragma unroll
        for (int r = 0; r < 4; ++r)
            ssum[r] += live ? __expf(acc[r] * factor) : 0.f;
    }
#pragma unroll
    for (int r = 0; r < 4; ++r)
#pragma unroll
        for (int off = 1; off < 16; off <<= 1)
            ssum[r] += __shfl_xor(ssum[r], off, 64);
    if (l16 == 0) {
#pragma unroll
        for (int r = 0; r < 4; ++r) wsum[w][lq * 4 + r] = ssum[r];
    }
    __syncthreads();
    float inv[4];
#pragma unroll
    for (int r = 0; r < 4; ++r) {
        const int row = lq * 4 + r;
        inv[r] = 1.f / (wsum[0][row] + wsum[1][row] + wsum[2][row] + wsum[3][row]);
    }

    // ---- sweep 2: attn write + PV ----
    f32x4 pv = {};
    float* abase = attn + ((size_t)((b * NH + h) * SQ_) + q0) * SK_;
    for (int t = 0; t < 32; ++t) {
        const int k0 = kw + t * 16;
        const __hip_bfloat16* Krow = &Kbase[(size_t)(k0 + l16) * HD];
        bf16x8 b0 = *(const bf16x8*)&Krow[lq * 8];
        bf16x8 b1 = *(const bf16x8*)&Krow[32 + lq * 8];
        f32x4 acc = {};
        acc = mfma16(a0, b0, acc);
        acc = mfma16(a1, b1, acc);
        const bool live = mbase[k0 + l16] != 0;
        const int colb = (t & 1) * 16 + l16;
#pragma unroll
        for (int r = 0; r < 4; ++r) {
            const float e = live ? __expf(acc[r] * factor) * inv[r] : 0.f;
            abase[(size_t)(lq * 4 + r) * SK_ + k0 + l16] = e;      // normalized fp32
            ptile[w][lq * 4 + r][colb] = __float2bfloat16(e);      // normalized bf16
        }
        if (t & 1) {
            const bf16x8 ap = *(const bf16x8*)&ptile[w][l16][lq * 8];
            const bf16x8 bp = *(const bf16x8*)&Vbase[(size_t)(w * 16 + l16) * SK_
                                                     + (kw + (t - 1) * 16) + lq * 8];
            pv = mfma16(ap, bp, pv);
        }
    }
#pragma unroll
    for (int r = 0; r < 4; ++r) {
        const int row = lq * 4 + r;
        ctx[((size_t)(b * SQ_) + q0 + row) * DM + h * HD + w * 16 + l16] = pv[r];
    }
}

// ---------------- in-place LayerNorm on d_out rows ----------------
__global__ __launch_bounds__(256)
void ln_kernel(float* __restrict__ x, const float* __restrict__ gamma,
               const float* __restrict__ beta)
{
    __shared__ float rb[8];
    const int row = blockIdx.x;
    const int tid = threadIdx.x;
    float v[3];
    float s = 0.f;
#pragma unroll
    for (int i = 0; i < 3; ++i) {
        v[i] = x[(size_t)row * DM + tid + i * 256];
        s += v[i];
    }
    s = blksum(s, rb, tid);
    const float mean = s * (1.0f / DM);
    float s2 = 0.f;
#pragma unroll
    for (int i = 0; i < 3; ++i) {
        const float d = v[i] - mean;
        s2 += d * d;
    }
    s2 = blksum(s2, rb, tid);
    const float rstd = rsqrtf(s2 * (1.0f / DM) + 1e-5f);
#pragma unroll
    for (int i = 0; i < 3; ++i) {
        const int c = tid + i * 256;
        x[(size_t)row * DM + c] = gamma[c] * (v[i] - mean) * rstd + beta[c];
    }
}

extern "C" void kernel_launch(void* const* d_in, const int* in_sizes, int n_in,
                              void* d_out, int out_size, void* d_ws, size_t ws_size,
                              hipStream_t stream)
{
    const float* query = (const float*)d_in[0];
    const float* key   = (const float*)d_in[1];
    const float* value = (const float*)d_in[2];
    const int*   mask  = (const int*)d_in[3];
    const float* Wq    = (const float*)d_in[4];
    const float* Wk    = (const float*)d_in[5];
    const float* Wv    = (const float*)d_in[6];
    const float* Wo    = (const float*)d_in[7];
    const float* bo    = (const float*)d_in[8];
    const float* gamma = (const float*)d_in[9];
    const float* beta  = (const float*)d_in[10];
    const float* temp  = (const float*)d_in[11];

    float* out  = (float*)d_out;                          // [B,SQ,DM]
    float* attn = out + (size_t)B_ * SQ_ * DM;            // [B,NH,SQ,SK] fp32

    __hip_bfloat16* Qb = (__hip_bfloat16*)d_ws;           // [B,NH,SQ,HD]
    __hip_bfloat16* Kb = Qb + (size_t)B_ * NH * SQ_ * HD; // [B,NH,SK,HD]
    __hip_bfloat16* Vt = Kb + (size_t)B_ * NH * SK_ * HD; // [B,NH,HD,SK]
    float* ctx = (float*)(Vt + (size_t)B_ * NH * SK_ * HD); // [B,SQ,DM] fp32
    // split scratch: separate regions for q,k,v (fused gemm reads all three)
    __hip_bfloat16* Shq = (__hip_bfloat16*)(ctx + (size_t)B_ * SQ_ * DM);
    __hip_bfloat16* Slq = Shq + (size_t)B_ * SQ_ * DM;
    __hip_bfloat16* Shk = Slq + (size_t)B_ * SQ_ * DM;
    __hip_bfloat16* Slk = Shk + (size_t)B_ * SK_ * DM;
    __hip_bfloat16* Shv = Slk + (size_t)B_ * SK_ * DM;
    __hip_bfloat16* Slv = Shv + (size_t)B_ * SK_ * DM;

    // weight transposes parked in not-yet-written regions:
    //   Wqt/Wkt/Wvt in ctx area (ctx produced later by attn); Wot in Qb (dead after attn)
    __hip_bfloat16* Wqt = (__hip_bfloat16*)ctx;
    __hip_bfloat16* Wkt = Wqt + (size_t)DM * DM;
    __hip_bfloat16* Wvt = Wkt + (size_t)DM * DM;
    __hip_bfloat16* Wot = Qb;

    const int n4_q = B_ * SQ_ * DM / 4;   // 786432  -> 3072 blocks

    dim3 blk(256);
    hipLaunchKernelGGL(transpose_cast, dim3(12, 12, 3), blk, 0, stream,
                       Wq, Wk, Wv, Wqt, Wkt, Wvt);

    hipLaunchKernelGGL(split3_bf16, dim3(15360), blk, 0, stream,
                       query, key, value, Shq, Slq, Shk, Slk, Shv, Slv);

    hipLaunchKernelGGL(gemm_qkv, dim3(960), blk, 0, stream,
                       Shq, Slq, Shk, Slk, Shv, Slv, Wqt, Wkt, Wvt, Qb, Kb, Vt);

    hipLaunchKernelGGL(attn_flash, dim3(B_ * NH * (SQ_ / QT)), blk, 0, stream,
                       Qb, Kb, Vt, mask, temp, attn, ctx);

    hipLaunchKernelGGL(transpose_cast, dim3(12, 12, 1), blk, 0, stream,
                       Wo, Wo, Wo, Wot, Wot, Wot);
    hipLaunchKernelGGL(split_bf16, dim3(n4_q / 256), blk, 0, stream, ctx, Shq, Slq);
    hipLaunchKernelGGL(gemm_o, dim3((B_ * SQ_ / 64) * (DM / 128)), blk, 0, stream,
                       Shq, Slq, Wot, out, bo, query);

    hipLaunchKernelGGL(ln_kernel, dim3(B_ * SQ_), blk, 0, stream, out, gamma, beta);
}

// Round 8
// 713.473 us; speedup vs baseline: 1.1850x; 1.1309x over previous
//
#include <hip/hip_runtime.h>
#include <hip/hip_bf16.h>
#include <math.h>

#define DM 768
#define NH 12
#define HD 64
#define B_ 4
#define SQ_ 1024
#define SK_ 2048
#define QT 16
#define PSTR 40   // p-tile LDS row stride (bf16 elems): 80 B, 16B-aligned, bank-clean

typedef __bf16 bf16x8 __attribute__((ext_vector_type(8)));
typedef __bf16 bf16x4 __attribute__((ext_vector_type(4)));
typedef float f32x4 __attribute__((ext_vector_type(4)));

static __device__ __forceinline__ f32x4 mfma16(bf16x8 a, bf16x8 b, f32x4 c) {
    return __builtin_amdgcn_mfma_f32_16x16x32_bf16(a, b, c, 0, 0, 0);
}

// async global->LDS, 16 B per lane (dest: wave-uniform base + lane*16)
static __device__ __forceinline__ void glds16(const void* g, void* l) {
    __builtin_amdgcn_global_load_lds(
        (const __attribute__((address_space(1))) void*)g,
        (__attribute__((address_space(3))) void*)l, 16, 0, 0);
}

// ---------------- block reductions (256 threads, 4 waves of 64) ----------------
__device__ __forceinline__ float blksum(float v, float* rb, int tid) {
#pragma unroll
    for (int off = 32; off; off >>= 1) v += __shfl_down(v, off, 64);
    if ((tid & 63) == 0) rb[tid >> 6] = v;
    __syncthreads();
    if (tid == 0) rb[4] = rb[0] + rb[1] + rb[2] + rb[3];
    __syncthreads();
    return rb[4];
}

// ---------------- W transpose + cast: Wt[n][k] bf16 from W[k][n] fp32 (4x) -----
__global__ __launch_bounds__(256)
void transpose_cast4(const float* __restrict__ W0, const float* __restrict__ W1,
                     const float* __restrict__ W2, const float* __restrict__ W3,
                     __hip_bfloat16* __restrict__ T0, __hip_bfloat16* __restrict__ T1,
                     __hip_bfloat16* __restrict__ T2, __hip_bfloat16* __restrict__ T3)
{
    __shared__ float Ls[64][68];
    const int z = blockIdx.z;
    const float* W = (z == 0) ? W0 : (z == 1) ? W1 : (z == 2) ? W2 : W3;
    __hip_bfloat16* T = (z == 0) ? T0 : (z == 1) ? T1 : (z == 2) ? T2 : T3;
    const int k0 = blockIdx.y * 64, n0 = blockIdx.x * 64;
    const int tid = threadIdx.x;
    const int kl = tid >> 4, n4 = (tid & 15) * 4;
#pragma unroll
    for (int p = 0; p < 4; ++p) {
        float4 v = *(const float4*)&W[(size_t)(k0 + kl + p * 16) * DM + n0 + n4];
        *(float4*)&Ls[kl + p * 16][n4] = v;
    }
    __syncthreads();
    const int nl = tid >> 2, kq = (tid & 3) * 16;
    __hip_bfloat16 tmp[16];
#pragma unroll
    for (int i = 0; i < 16; ++i) tmp[i] = __float2bfloat16(Ls[kq + i][nl]);
    *(bf16x8*)&T[(size_t)(n0 + nl) * DM + k0 + kq]     = *(bf16x8*)&tmp[0];
    *(bf16x8*)&T[(size_t)(n0 + nl) * DM + k0 + kq + 8] = *(bf16x8*)&tmp[8];
}

// ---------------- fp32 -> (hi, lo) bf16 split ---------------------------------
__device__ __forceinline__ void split_body(const float* __restrict__ X,
                                           __hip_bfloat16* __restrict__ Xh,
                                           __hip_bfloat16* __restrict__ Xl, int i)
{
    float4 v = ((const float4*)X)[i];
    float xs[4] = {v.x, v.y, v.z, v.w};
    bf16x4 h, l;
#pragma unroll
    for (int e = 0; e < 4; ++e) {
        const __bf16 hh = (__bf16)xs[e];
        h[e] = hh;
        l[e] = (__bf16)(xs[e] - (float)hh);
    }
    *(bf16x4*)&Xh[(size_t)i * 4] = h;
    *(bf16x4*)&Xl[(size_t)i * 4] = l;
}

// fused q/k/v split: blocks [0,3072) q, [3072,9216) k, [9216,15360) v
__global__ __launch_bounds__(256)
void split3_bf16(const float* __restrict__ q, const float* __restrict__ k,
                 const float* __restrict__ v,
                 __hip_bfloat16* __restrict__ qh, __hip_bfloat16* __restrict__ ql,
                 __hip_bfloat16* __restrict__ kh, __hip_bfloat16* __restrict__ kl,
                 __hip_bfloat16* __restrict__ vh, __hip_bfloat16* __restrict__ vl)
{
    const int b = blockIdx.x;
    const float* X; __hip_bfloat16 *H, *L; int base;
    if (b < 3072)      { X = q; H = qh; L = ql; base = b; }
    else if (b < 9216) { X = k; H = kh; L = kl; base = b - 3072; }
    else               { X = v; H = vh; L = vl; base = b - 9216; }
    split_body(X, H, L, base * 256 + threadIdx.x);
}

// ---------------- bf16 MFMA GEMM body (m97 structure) --------------------------
// C[M x 768] = A @ Wt^T  (A = Ahg [+ Alg if DUAL]), Wt[n][k] bf16.
// BM x 128 tile, BK=32, 256 thr (4 waves 2x2), global_load_lds(16B) -> linear
// LDS, double-buffered, one barrier per K-chunk.
// mode 0: bf16 head-split; mode 1: fp32 + bias + resid; mode 2: bf16 transposed.
template <int BM, bool DUAL>
__device__ __forceinline__ void gemm_body(
    const __hip_bfloat16* __restrict__ Ahg, const __hip_bfloat16* __restrict__ Alg,
    const __hip_bfloat16* __restrict__ Wt,
    float* __restrict__ outf, __hip_bfloat16* __restrict__ outb, int S,
    const float* __restrict__ bias, const float* __restrict__ resid,
    int lbid, int mode)
{
    constexpr int NI = BM / 32;            // row frags per wave
    constexpr int ABYTES = BM * 64;        // bytes per A buffer
    __shared__ __align__(16) __hip_bfloat16 sAh[2][BM][32];
    __shared__ __align__(16) __hip_bfloat16 sAl[DUAL ? 2 : 1][BM][32];
    __shared__ __align__(16) __hip_bfloat16 sWs[2][128][32];

    const int tid  = threadIdx.x;
    const int lane = tid & 63;
    const int w    = tid >> 6;
    const int l16  = lane & 15;
    const int lq   = lane >> 4;
    const int wr   = w >> 1, wc = w & 1;

    const int bn = lbid % (DM / 128);
    const int bm = lbid / (DM / 128);
    const int row0 = bm * BM, col0 = bn * 128;

    const int sr  = tid >> 2;              // staging row 0..63
    const int sc8 = (tid & 3) * 8;

    char* const dA = (char*)&sAh[0][0][0] + tid * 16;
    char* const dL = (char*)&sAl[0][0][0] + tid * 16;
    char* const dW = (char*)&sWs[0][0][0] + tid * 16;

    auto issue = [&](int buf, int k0) {
        const size_t ao = (size_t)(row0 + sr) * DM + k0 + sc8;
        const size_t wo = (size_t)(col0 + sr) * DM + k0 + sc8;
        glds16(Ahg + ao, dA + buf * ABYTES);
        if constexpr (DUAL) glds16(Alg + ao, dL + buf * ABYTES);
        if constexpr (BM == 128) {
            glds16(Ahg + ao + (size_t)64 * DM, dA + buf * ABYTES + 4096);
            if constexpr (DUAL) glds16(Alg + ao + (size_t)64 * DM, dL + buf * ABYTES + 4096);
        }
        glds16(Wt + wo,                 dW + buf * 8192);
        glds16(Wt + wo + (size_t)64*DM, dW + buf * 8192 + 4096);
    };

    f32x4 acc[NI][4] = {};
    issue(0, 0);
    int cur = 0;
    for (int c = 0; c < DM / 32; ++c) {
        __syncthreads();                   // buf[cur] landed; readers of cur^1 done
        if (c + 1 < DM / 32) issue(cur ^ 1, (c + 1) * 32);

        bf16x8 bfr[4];
#pragma unroll
        for (int j = 0; j < 4; ++j)
            bfr[j] = *(const bf16x8*)&sWs[cur][wc * 64 + j * 16 + l16][lq * 8];
#pragma unroll
        for (int i = 0; i < NI; ++i) {
            const bf16x8 ah = *(const bf16x8*)&sAh[cur][wr * (BM/2) + i * 16 + l16][lq * 8];
#pragma unroll
            for (int j = 0; j < 4; ++j)
                acc[i][j] = mfma16(ah, bfr[j], acc[i][j]);
            if constexpr (DUAL) {
                const bf16x8 al = *(const bf16x8*)&sAl[cur][wr * (BM/2) + i * 16 + l16][lq * 8];
#pragma unroll
                for (int j = 0; j < 4; ++j)
                    acc[i][j] = mfma16(al, bfr[j], acc[i][j]);
            }
        }
        cur ^= 1;
    }

    // ---- epilogue: row = row0+wr*(BM/2)+i*16+lq*4+rr, col = col0+wc*64+j*16+l16
    int b_blk = 0, s_base = 0;
    if (mode != 1) {
        b_blk  = row0 / S;
        s_base = row0 - b_blk * S + wr * (BM / 2);
    }
#pragma unroll
    for (int i = 0; i < NI; ++i) {
#pragma unroll
        for (int j = 0; j < 4; ++j) {
#pragma unroll
            for (int rr = 0; rr < 4; ++rr) {
                const int cc = col0 + wc * 64 + j * 16 + l16;
                if (mode == 1) {
                    const int r = row0 + wr * (BM/2) + i * 16 + lq * 4 + rr;
                    outf[(size_t)r * DM + cc] =
                        acc[i][j][rr] + bias[cc] + resid[(size_t)r * DM + cc];
                } else {
                    const int s  = s_base + i * 16 + lq * 4 + rr;
                    const int h  = cc >> 6, hd = cc & 63;
                    if (mode == 0)
                        outb[(((size_t)b_blk * NH + h) * S + s) * HD + hd] =
                            __float2bfloat16(acc[i][j][rr]);
                    else
                        outb[(((size_t)b_blk * NH + h) * HD + hd) * S + s] =
                            __float2bfloat16(acc[i][j][rr]);
                }
            }
        }
    }
}

// fused QKV projection, XCD-chunked swizzle (960 = 8*120):
// lbid [0,192) Q, [192,576) K, [576,960) V
__global__ __launch_bounds__(256)
void gemm_qkv(const __hip_bfloat16* __restrict__ qh, const __hip_bfloat16* __restrict__ ql,
              const __hip_bfloat16* __restrict__ kh, const __hip_bfloat16* __restrict__ kl,
              const __hip_bfloat16* __restrict__ vh, const __hip_bfloat16* __restrict__ vl,
              const __hip_bfloat16* __restrict__ Wqt, const __hip_bfloat16* __restrict__ Wkt,
              const __hip_bfloat16* __restrict__ Wvt,
              __hip_bfloat16* __restrict__ Qb, __hip_bfloat16* __restrict__ Kb,
              __hip_bfloat16* __restrict__ Vt)
{
    const int bid  = blockIdx.x;
    const int lbid = (bid & 7) * 120 + (bid >> 3);
    if (lbid < 192)
        gemm_body<128, true>(qh, ql, Wqt, nullptr, Qb, SQ_, nullptr, nullptr, lbid, 0);
    else if (lbid < 576)
        gemm_body<128, true>(kh, kl, Wkt, nullptr, Kb, SK_, nullptr, nullptr, lbid - 192, 0);
    else
        gemm_body<128, true>(vh, vl, Wvt, nullptr, Vt, SK_, nullptr, nullptr, lbid - 576, 2);
}

// O projection: BM=64, single bf16 A (ctx), fp32 out + bias + residual (384 = 8*48)
__global__ __launch_bounds__(256)
void gemm_o(const __hip_bfloat16* __restrict__ a, const __hip_bfloat16* __restrict__ Wot,
            float* __restrict__ outf, const float* __restrict__ bias,
            const float* __restrict__ resid)
{
    const int bid  = blockIdx.x;
    const int lbid = (bid & 7) * 48 + (bid >> 3);
    gemm_body<64, false>(a, nullptr, Wot, outf, nullptr, SQ_, bias, resid, lbid, 1);
}

// ---------------- flash attention, p held in registers -------------------------
// Sweep 1: QK^T + exp; p packed to bf16 pairs in 64 VGPRs; row-sums in regs.
// Sweep 2 (no recompute): unpack, normalize, write fp32 attn, stage per-wave
// 16x32 bf16 p-tile (stride PSTR), PV MFMA every 2 tiles. ctx written as bf16.
// Wave w: k-strip [512w,512w+512), PV d-tile [16w,16w+16). XCD swizzle 3072=8*384.
__global__ __launch_bounds__(256)
void attn_flash(const __hip_bfloat16* __restrict__ Qb,
                const __hip_bfloat16* __restrict__ Kb,
                const __hip_bfloat16* __restrict__ Vt,
                const int* __restrict__ mask, const float* __restrict__ temp,
                float* __restrict__ attn, __hip_bfloat16* __restrict__ ctx)
{
    __shared__ float wsum[4][16];
    __shared__ __align__(16) __hip_bfloat16 ptile[4][16][PSTR];

    const int tid  = threadIdx.x;
    const int lane = tid & 63;
    const int w    = tid >> 6;
    const int l16  = lane & 15;
    const int lq   = lane >> 4;

    const int bid = blockIdx.x;
    const int lb  = (bid & 7) * 384 + (bid >> 3);
    const int nqt = SQ_ / QT;                  // 64
    const int qt  = lb % nqt;
    const int h   = (lb / nqt) % NH;
    const int b   = lb / (nqt * NH);
    const int q0  = qt * QT;

    const float factor = 0.125f / temp[0];

    const __hip_bfloat16* Qbase = Qb + (((size_t)b * NH + h) * SQ_ + q0) * HD;
    const __hip_bfloat16* Kbase = Kb + ((size_t)b * NH + h) * SK_ * HD;
    const __hip_bfloat16* Vbase = Vt + ((size_t)b * NH + h) * HD * SK_;
    const int* mbase = mask + b * SK_;

    const bf16x8 a0 = *(const bf16x8*)&Qbase[(size_t)l16 * HD + lq * 8];
    const bf16x8 a1 = *(const bf16x8*)&Qbase[(size_t)l16 * HD + 32 + lq * 8];

    const int kw = w * 512;

    // ---- sweep 1: QK^T + exp -> packed bf16 p in registers, row sums ----
    unsigned int pk[64];                       // [t][r>>1], static-indexed (unrolled)
    float ssum[4] = {0.f, 0.f, 0.f, 0.f};
#pragma unroll
    for (int t = 0; t < 32; ++t) {
        const int k0 = kw + t * 16;
        const __hip_bfloat16* Krow = &Kbase[(size_t)(k0 + l16) * HD];
        bf16x8 b0 = *(const bf16x8*)&Krow[lq * 8];
        bf16x8 b1 = *(const bf16x8*)&Krow[32 + lq * 8];
        f32x4 acc = {};
        acc = mfma16(a0, b0, acc);
        acc = mfma16(a1, b1, acc);
        const bool live = mbase[k0 + l16] != 0;
        float e[4];
#pragma unroll
        for (int r = 0; r < 4; ++r) {
            e[r] = live ? __expf(acc[r] * factor) : 0.f;
            ssum[r] += e[r];
        }
#pragma unroll
        for (int hh = 0; hh < 2; ++hh) {
            const unsigned short u0 = __builtin_bit_cast(unsigned short, (__bf16)e[2 * hh]);
            const unsigned short u1 = __builtin_bit_cast(unsigned short, (__bf16)e[2 * hh + 1]);
            pk[t * 2 + hh] = (unsigned int)u0 | ((unsigned int)u1 << 16);
        }
    }
#pragma unroll
    for (int r = 0; r < 4; ++r)
#pragma unroll
        for (int off = 1; off < 16; off <<= 1)
            ssum[r] += __shfl_xor(ssum[r], off, 64);
    if (l16 == 0) {
#pragma unroll
        for (int r = 0; r < 4; ++r) wsum[w][lq * 4 + r] = ssum[r];
    }
    __syncthreads();
    float inv[4];
#pragma unroll
    for (int r = 0; r < 4; ++r) {
        const int row = lq * 4 + r;
        inv[r] = 1.f / (wsum[0][row] + wsum[1][row] + wsum[2][row] + wsum[3][row]);
    }

    // ---- sweep 2: normalize + attn write + PV (no recompute) ----
    f32x4 pv = {};
    float* abase = attn + ((size_t)((b * NH + h) * SQ_) + q0) * SK_;
#pragma unroll
    for (int t = 0; t < 32; ++t) {
        const int k0 = kw + t * 16;
        const int colb = (t & 1) * 16 + l16;
#pragma unroll
        for (int r = 0; r < 4; ++r) {
            const __bf16 pb = __builtin_bit_cast(
                __bf16, (unsigned short)(pk[t * 2 + (r >> 1)] >> (16 * (r & 1))));
            const float e = (float)pb * inv[r];
            abase[(size_t)(lq * 4 + r) * SK_ + k0 + l16] = e;      // normalized fp32
            ptile[w][lq * 4 + r][colb] = __float2bfloat16(e);      // normalized bf16
        }
        if (t & 1) {
            const bf16x8 ap = *(const bf16x8*)&ptile[w][l16][lq * 8];
            const bf16x8 bp = *(const bf16x8*)&Vbase[(size_t)(w * 16 + l16) * SK_
                                                     + (kw + (t - 1) * 16) + lq * 8];
            pv = mfma16(ap, bp, pv);
        }
    }
#pragma unroll
    for (int r = 0; r < 4; ++r) {
        const int row = lq * 4 + r;
        ctx[((size_t)(b * SQ_) + q0 + row) * DM + h * HD + w * 16 + l16] =
            __float2bfloat16(pv[r]);
    }
}

// ---------------- in-place LayerNorm on d_out rows ----------------
__global__ __launch_bounds__(256)
void ln_kernel(float* __restrict__ x, const float* __restrict__ gamma,
               const float* __restrict__ beta)
{
    __shared__ float rb[8];
    const int row = blockIdx.x;
    const int tid = threadIdx.x;
    float v[3];
    float s = 0.f;
#pragma unroll
    for (int i = 0; i < 3; ++i) {
        v[i] = x[(size_t)row * DM + tid + i * 256];
        s += v[i];
    }
    s = blksum(s, rb, tid);
    const float mean = s * (1.0f / DM);
    float s2 = 0.f;
#pragma unroll
    for (int i = 0; i < 3; ++i) {
        const float d = v[i] - mean;
        s2 += d * d;
    }
    s2 = blksum(s2, rb, tid);
    const float rstd = rsqrtf(s2 * (1.0f / DM) + 1e-5f);
#pragma unroll
    for (int i = 0; i < 3; ++i) {
        const int c = tid + i * 256;
        x[(size_t)row * DM + c] = gamma[c] * (v[i] - mean) * rstd + beta[c];
    }
}

extern "C" void kernel_launch(void* const* d_in, const int* in_sizes, int n_in,
                              void* d_out, int out_size, void* d_ws, size_t ws_size,
                              hipStream_t stream)
{
    const float* query = (const float*)d_in[0];
    const float* key   = (const float*)d_in[1];
    const float* value = (const float*)d_in[2];
    const int*   mask  = (const int*)d_in[3];
    const float* Wq    = (const float*)d_in[4];
    const float* Wk    = (const float*)d_in[5];
    const float* Wv    = (const float*)d_in[6];
    const float* Wo    = (const float*)d_in[7];
    const float* bo    = (const float*)d_in[8];
    const float* gamma = (const float*)d_in[9];
    const float* beta  = (const float*)d_in[10];
    const float* temp  = (const float*)d_in[11];

    float* out  = (float*)d_out;                          // [B,SQ,DM]
    float* attn = out + (size_t)B_ * SQ_ * DM;            // [B,NH,SQ,SK] fp32

    __hip_bfloat16* Qb = (__hip_bfloat16*)d_ws;           // [B,NH,SQ,HD]
    __hip_bfloat16* Kb = Qb + (size_t)B_ * NH * SQ_ * HD; // [B,NH,SK,HD]
    __hip_bfloat16* Vt = Kb + (size_t)B_ * NH * SK_ * HD; // [B,NH,HD,SK]
    // C-region (was fp32 ctx, 12.6 MB): 4 weight transposes + bf16 ctx
    __hip_bfloat16* Cb  = Vt + (size_t)B_ * NH * SK_ * HD;
    __hip_bfloat16* Wqt = Cb;
    __hip_bfloat16* Wkt = Wqt + (size_t)DM * DM;
    __hip_bfloat16* Wvt = Wkt + (size_t)DM * DM;
    __hip_bfloat16* Wot = Wvt + (size_t)DM * DM;
    __hip_bfloat16* ctxb = Wot + (size_t)DM * DM;         // [B,SQ,DM] bf16
    // split scratch
    __hip_bfloat16* Shq = ctxb + (size_t)B_ * SQ_ * DM;
    __hip_bfloat16* Slq = Shq + (size_t)B_ * SQ_ * DM;
    __hip_bfloat16* Shk = Slq + (size_t)B_ * SQ_ * DM;
    __hip_bfloat16* Slk = Shk + (size_t)B_ * SK_ * DM;
    __hip_bfloat16* Shv = Slk + (size_t)B_ * SK_ * DM;
    __hip_bfloat16* Slv = Shv + (size_t)B_ * SK_ * DM;

    dim3 blk(256);
    hipLaunchKernelGGL(transpose_cast4, dim3(12, 12, 4), blk, 0, stream,
                       Wq, Wk, Wv, Wo, Wqt, Wkt, Wvt, Wot);

    hipLaunchKernelGGL(split3_bf16, dim3(15360), blk, 0, stream,
                       query, key, value, Shq, Slq, Shk, Slk, Shv, Slv);

    hipLaunchKernelGGL(gemm_qkv, dim3(960), blk, 0, stream,
                       Shq, Slq, Shk, Slk, Shv, Slv, Wqt, Wkt, Wvt, Qb, Kb, Vt);

    hipLaunchKernelGGL(attn_flash, dim3(B_ * NH * (SQ_ / QT)), blk, 0, stream,
                       Qb, Kb, Vt, mask, temp, attn, ctxb);

    hipLaunchKernelGGL(gemm_o, dim3((B_ * SQ_ / 64) * (DM / 128)), blk, 0, stream,
                       ctxb, Wot, out, bo, query);

    hipLaunchKernelGGL(ln_kernel, dim3(B_ * SQ_), blk, 0, stream, out, gamma, beta);
}

// Round 9
// 673.341 us; speedup vs baseline: 1.2557x; 1.0596x over previous
//
#include <hip/hip_runtime.h>
#include <hip/hip_bf16.h>
#include <math.h>

#define DM 768
#define NH 12
#define HD 64
#define B_ 4
#define SQ_ 1024
#define SK_ 2048
#define QT 16
#define PSTR 40   // p-tile LDS row stride (bf16 elems): 80 B, 16B-aligned, bank-clean

typedef __bf16 bf16x8 __attribute__((ext_vector_type(8)));
typedef __bf16 bf16x4 __attribute__((ext_vector_type(4)));
typedef float f32x4 __attribute__((ext_vector_type(4)));

static __device__ __forceinline__ f32x4 mfma16(bf16x8 a, bf16x8 b, f32x4 c) {
    return __builtin_amdgcn_mfma_f32_16x16x32_bf16(a, b, c, 0, 0, 0);
}

// async global->LDS, 16 B per lane (dest: wave-uniform base + lane*16)
static __device__ __forceinline__ void glds16(const void* g, void* l) {
    __builtin_amdgcn_global_load_lds(
        (const __attribute__((address_space(1))) void*)g,
        (__attribute__((address_space(3))) void*)l, 16, 0, 0);
}

// ---------------- block reductions (256 threads, 4 waves of 64) ----------------
__device__ __forceinline__ float blksum(float v, float* rb, int tid) {
#pragma unroll
    for (int off = 32; off; off >>= 1) v += __shfl_down(v, off, 64);
    if ((tid & 63) == 0) rb[tid >> 6] = v;
    __syncthreads();
    if (tid == 0) rb[4] = rb[0] + rb[1] + rb[2] + rb[3];
    __syncthreads();
    return rb[4];
}

// ---------------- W transpose + cast: Wt[n][k] bf16 from W[k][n] fp32 (4x) -----
__global__ __launch_bounds__(256)
void transpose_cast4(const float* __restrict__ W0, const float* __restrict__ W1,
                     const float* __restrict__ W2, const float* __restrict__ W3,
                     __hip_bfloat16* __restrict__ T0, __hip_bfloat16* __restrict__ T1,
                     __hip_bfloat16* __restrict__ T2, __hip_bfloat16* __restrict__ T3)
{
    __shared__ float Ls[64][68];
    const int z = blockIdx.z;
    const float* W = (z == 0) ? W0 : (z == 1) ? W1 : (z == 2) ? W2 : W3;
    __hip_bfloat16* T = (z == 0) ? T0 : (z == 1) ? T1 : (z == 2) ? T2 : T3;
    const int k0 = blockIdx.y * 64, n0 = blockIdx.x * 64;
    const int tid = threadIdx.x;
    const int kl = tid >> 4, n4 = (tid & 15) * 4;
#pragma unroll
    for (int p = 0; p < 4; ++p) {
        float4 v = *(const float4*)&W[(size_t)(k0 + kl + p * 16) * DM + n0 + n4];
        *(float4*)&Ls[kl + p * 16][n4] = v;
    }
    __syncthreads();
    const int nl = tid >> 2, kq = (tid & 3) * 16;
    __hip_bfloat16 tmp[16];
#pragma unroll
    for (int i = 0; i < 16; ++i) tmp[i] = __float2bfloat16(Ls[kq + i][nl]);
    *(bf16x8*)&T[(size_t)(n0 + nl) * DM + k0 + kq]     = *(bf16x8*)&tmp[0];
    *(bf16x8*)&T[(size_t)(n0 + nl) * DM + k0 + kq + 8] = *(bf16x8*)&tmp[8];
}

// ---------------- fp32 -> bf16 cast (no hi/lo split: sub-quantization) --------
__device__ __forceinline__ void cast_body(const float* __restrict__ X,
                                          __hip_bfloat16* __restrict__ Xh, int i)
{
    float4 v = ((const float4*)X)[i];
    float xs[4] = {v.x, v.y, v.z, v.w};
    bf16x4 h;
#pragma unroll
    for (int e = 0; e < 4; ++e) h[e] = (__bf16)xs[e];
    *(bf16x4*)&Xh[(size_t)i * 4] = h;
}

// fused q/k/v cast: blocks [0,3072) q, [3072,9216) k, [9216,15360) v
__global__ __launch_bounds__(256)
void cast3_bf16(const float* __restrict__ q, const float* __restrict__ k,
                const float* __restrict__ v,
                __hip_bfloat16* __restrict__ qh, __hip_bfloat16* __restrict__ kh,
                __hip_bfloat16* __restrict__ vh)
{
    const int b = blockIdx.x;
    const float* X; __hip_bfloat16* H; int base;
    if (b < 3072)      { X = q; H = qh; base = b; }
    else if (b < 9216) { X = k; H = kh; base = b - 3072; }
    else               { X = v; H = vh; base = b - 9216; }
    cast_body(X, H, base * 256 + threadIdx.x);
}

// ---------------- bf16 MFMA GEMM body (m97 structure) --------------------------
// C[M x 768] = A @ Wt^T, A bf16, Wt[n][k] bf16. BM x 128 tile, BK=32,
// 256 thr (4 waves 2x2), global_load_lds(16B) -> linear LDS, double-buffered,
// one barrier per K-chunk.
// mode 0: bf16 head-split; mode 1: fp32 + bias + resid; mode 2: bf16 transposed.
template <int BM>
__device__ __forceinline__ void gemm_body(
    const __hip_bfloat16* __restrict__ Ahg, const __hip_bfloat16* __restrict__ Wt,
    float* __restrict__ outf, __hip_bfloat16* __restrict__ outb, int S,
    const float* __restrict__ bias, const float* __restrict__ resid,
    int lbid, int mode)
{
    constexpr int NI = BM / 32;            // row frags per wave
    constexpr int ABYTES = BM * 64;        // bytes per A buffer
    __shared__ __align__(16) __hip_bfloat16 sAh[2][BM][32];
    __shared__ __align__(16) __hip_bfloat16 sWs[2][128][32];

    const int tid  = threadIdx.x;
    const int lane = tid & 63;
    const int w    = tid >> 6;
    const int l16  = lane & 15;
    const int lq   = lane >> 4;
    const int wr   = w >> 1, wc = w & 1;

    const int bn = lbid % (DM / 128);
    const int bm = lbid / (DM / 128);
    const int row0 = bm * BM, col0 = bn * 128;

    const int sr  = tid >> 2;              // staging row 0..63
    const int sc8 = (tid & 3) * 8;

    char* const dA = (char*)&sAh[0][0][0] + tid * 16;
    char* const dW = (char*)&sWs[0][0][0] + tid * 16;

    auto issue = [&](int buf, int k0) {
        const size_t ao = (size_t)(row0 + sr) * DM + k0 + sc8;
        const size_t wo = (size_t)(col0 + sr) * DM + k0 + sc8;
        glds16(Ahg + ao, dA + buf * ABYTES);
        if constexpr (BM == 128)
            glds16(Ahg + ao + (size_t)64 * DM, dA + buf * ABYTES + 4096);
        glds16(Wt + wo,                 dW + buf * 8192);
        glds16(Wt + wo + (size_t)64*DM, dW + buf * 8192 + 4096);
    };

    f32x4 acc[NI][4] = {};
    issue(0, 0);
    int cur = 0;
    for (int c = 0; c < DM / 32; ++c) {
        __syncthreads();                   // buf[cur] landed; readers of cur^1 done
        if (c + 1 < DM / 32) issue(cur ^ 1, (c + 1) * 32);

        bf16x8 bfr[4];
#pragma unroll
        for (int j = 0; j < 4; ++j)
            bfr[j] = *(const bf16x8*)&sWs[cur][wc * 64 + j * 16 + l16][lq * 8];
#pragma unroll
        for (int i = 0; i < NI; ++i) {
            const bf16x8 ah = *(const bf16x8*)&sAh[cur][wr * (BM/2) + i * 16 + l16][lq * 8];
#pragma unroll
            for (int j = 0; j < 4; ++j)
                acc[i][j] = mfma16(ah, bfr[j], acc[i][j]);
        }
        cur ^= 1;
    }

    // ---- epilogue: row = row0+wr*(BM/2)+i*16+lq*4+rr, col = col0+wc*64+j*16+l16
    int b_blk = 0, s_base = 0;
    if (mode != 1) {
        b_blk  = row0 / S;
        s_base = row0 - b_blk * S + wr * (BM / 2);
    }
#pragma unroll
    for (int i = 0; i < NI; ++i) {
#pragma unroll
        for (int j = 0; j < 4; ++j) {
#pragma unroll
            for (int rr = 0; rr < 4; ++rr) {
                const int cc = col0 + wc * 64 + j * 16 + l16;
                if (mode == 1) {
                    const int r = row0 + wr * (BM/2) + i * 16 + lq * 4 + rr;
                    outf[(size_t)r * DM + cc] =
                        acc[i][j][rr] + bias[cc] + resid[(size_t)r * DM + cc];
                } else {
                    const int s  = s_base + i * 16 + lq * 4 + rr;
                    const int h  = cc >> 6, hd = cc & 63;
                    if (mode == 0)
                        outb[(((size_t)b_blk * NH + h) * S + s) * HD + hd] =
                            __float2bfloat16(acc[i][j][rr]);
                    else
                        outb[(((size_t)b_blk * NH + h) * HD + hd) * S + s] =
                            __float2bfloat16(acc[i][j][rr]);
                }
            }
        }
    }
}

// fused QKV projection, XCD-chunked swizzle (960 = 8*120):
// lbid [0,192) Q, [192,576) K, [576,960) V
__global__ __launch_bounds__(256)
void gemm_qkv(const __hip_bfloat16* __restrict__ qh, const __hip_bfloat16* __restrict__ kh,
              const __hip_bfloat16* __restrict__ vh,
              const __hip_bfloat16* __restrict__ Wqt, const __hip_bfloat16* __restrict__ Wkt,
              const __hip_bfloat16* __restrict__ Wvt,
              __hip_bfloat16* __restrict__ Qb, __hip_bfloat16* __restrict__ Kb,
              __hip_bfloat16* __restrict__ Vt)
{
    const int bid  = blockIdx.x;
    const int lbid = (bid & 7) * 120 + (bid >> 3);
    if (lbid < 192)
        gemm_body<128>(qh, Wqt, nullptr, Qb, SQ_, nullptr, nullptr, lbid, 0);
    else if (lbid < 576)
        gemm_body<128>(kh, Wkt, nullptr, Kb, SK_, nullptr, nullptr, lbid - 192, 0);
    else
        gemm_body<128>(vh, Wvt, nullptr, Vt, SK_, nullptr, nullptr, lbid - 576, 2);
}

// O projection: BM=64, bf16 A (ctx), fp32 out + bias + residual (384 = 8*48)
__global__ __launch_bounds__(256)
void gemm_o(const __hip_bfloat16* __restrict__ a, const __hip_bfloat16* __restrict__ Wot,
            float* __restrict__ outf, const float* __restrict__ bias,
            const float* __restrict__ resid)
{
    const int bid  = blockIdx.x;
    const int lbid = (bid & 7) * 48 + (bid >> 3);
    gemm_body<64>(a, Wot, outf, nullptr, SQ_, bias, resid, lbid, 1);
}

// ---------------- flash attention, p held in registers -------------------------
// Sweep 1: QK^T + exp; p packed to bf16 pairs in 64 VGPRs; row-sums in regs.
// Sweep 2 (no recompute): unpack, normalize, write fp32 attn, stage per-wave
// 16x32 bf16 p-tile (stride PSTR), PV MFMA every 2 tiles. ctx written as bf16.
// Wave w: k-strip [512w,512w+512), PV d-tile [16w,16w+16). XCD swizzle 3072=8*384.
__global__ __launch_bounds__(256)
void attn_flash(const __hip_bfloat16* __restrict__ Qb,
                const __hip_bfloat16* __restrict__ Kb,
                const __hip_bfloat16* __restrict__ Vt,
                const int* __restrict__ mask, const float* __restrict__ temp,
                float* __restrict__ attn, __hip_bfloat16* __restrict__ ctx)
{
    __shared__ float wsum[4][16];
    __shared__ __align__(16) __hip_bfloat16 ptile[4][16][PSTR];

    const int tid  = threadIdx.x;
    const int lane = tid & 63;
    const int w    = tid >> 6;
    const int l16  = lane & 15;
    const int lq   = lane >> 4;

    const int bid = blockIdx.x;
    const int lb  = (bid & 7) * 384 + (bid >> 3);
    const int nqt = SQ_ / QT;                  // 64
    const int qt  = lb % nqt;
    const int h   = (lb / nqt) % NH;
    const int b   = lb / (nqt * NH);
    const int q0  = qt * QT;

    const float factor = 0.125f / temp[0];

    const __hip_bfloat16* Qbase = Qb + (((size_t)b * NH + h) * SQ_ + q0) * HD;
    const __hip_bfloat16* Kbase = Kb + ((size_t)b * NH + h) * SK_ * HD;
    const __hip_bfloat16* Vbase = Vt + ((size_t)b * NH + h) * HD * SK_;
    const int* mbase = mask + b * SK_;

    const bf16x8 a0 = *(const bf16x8*)&Qbase[(size_t)l16 * HD + lq * 8];
    const bf16x8 a1 = *(const bf16x8*)&Qbase[(size_t)l16 * HD + 32 + lq * 8];

    const int kw = w * 512;

    // ---- sweep 1: QK^T + exp -> packed bf16 p in registers, row sums ----
    unsigned int pk[64];                       // [t][r>>1], static-indexed (unrolled)
    float ssum[4] = {0.f, 0.f, 0.f, 0.f};
#pragma unroll
    for (int t = 0; t < 32; ++t) {
        const int k0 = kw + t * 16;
        const __hip_bfloat16* Krow = &Kbase[(size_t)(k0 + l16) * HD];
        bf16x8 b0 = *(const bf16x8*)&Krow[lq * 8];
        bf16x8 b1 = *(const bf16x8*)&Krow[32 + lq * 8];
        f32x4 acc = {};
        acc = mfma16(a0, b0, acc);
        acc = mfma16(a1, b1, acc);
        const bool live = mbase[k0 + l16] != 0;
        float e[4];
#pragma unroll
        for (int r = 0; r < 4; ++r) {
            e[r] = live ? __expf(acc[r] * factor) : 0.f;
            ssum[r] += e[r];
        }
#pragma unroll
        for (int hh = 0; hh < 2; ++hh) {
            const unsigned short u0 = __builtin_bit_cast(unsigned short, (__bf16)e[2 * hh]);
            const unsigned short u1 = __builtin_bit_cast(unsigned short, (__bf16)e[2 * hh + 1]);
            pk[t * 2 + hh] = (unsigned int)u0 | ((unsigned int)u1 << 16);
        }
    }
#pragma unroll
    for (int r = 0; r < 4; ++r)
#pragma unroll
        for (int off = 1; off < 16; off <<= 1)
            ssum[r] += __shfl_xor(ssum[r], off, 64);
    if (l16 == 0) {
#pragma unroll
        for (int r = 0; r < 4; ++r) wsum[w][lq * 4 + r] = ssum[r];
    }
    __syncthreads();
    float inv[4];
#pragma unroll
    for (int r = 0; r < 4; ++r) {
        const int row = lq * 4 + r;
        inv[r] = 1.f / (wsum[0][row] + wsum[1][row] + wsum[2][row] + wsum[3][row]);
    }

    // ---- sweep 2: normalize + attn write + PV (no recompute) ----
    f32x4 pv = {};
    float* abase = attn + ((size_t)((b * NH + h) * SQ_) + q0) * SK_;
#pragma unroll
    for (int t = 0; t < 32; ++t) {
        const int k0 = kw + t * 16;
        const int colb = (t & 1) * 16 + l16;
#pragma unroll
        for (int r = 0; r < 4; ++r) {
            const __bf16 pb = __builtin_bit_cast(
                __bf16, (unsigned short)(pk[t * 2 + (r >> 1)] >> (16 * (r & 1))));
            const float e = (float)pb * inv[r];
            abase[(size_t)(lq * 4 + r) * SK_ + k0 + l16] = e;      // normalized fp32
            ptile[w][lq * 4 + r][colb] = __float2bfloat16(e);      // normalized bf16
        }
        if (t & 1) {
            const bf16x8 ap = *(const bf16x8*)&ptile[w][l16][lq * 8];
            const bf16x8 bp = *(const bf16x8*)&Vbase[(size_t)(w * 16 + l16) * SK_
                                                     + (kw + (t - 1) * 16) + lq * 8];
            pv = mfma16(ap, bp, pv);
        }
    }
#pragma unroll
    for (int r = 0; r < 4; ++r) {
        const int row = lq * 4 + r;
        ctx[((size_t)(b * SQ_) + q0 + row) * DM + h * HD + w * 16 + l16] =
            __float2bfloat16(pv[r]);
    }
}

// ---------------- in-place LayerNorm on d_out rows ----------------
__global__ __launch_bounds__(256)
void ln_kernel(float* __restrict__ x, const float* __restrict__ gamma,
               const float* __restrict__ beta)
{
    __shared__ float rb[8];
    const int row = blockIdx.x;
    const int tid = threadIdx.x;
    float v[3];
    float s = 0.f;
#pragma unroll
    for (int i = 0; i < 3; ++i) {
        v[i] = x[(size_t)row * DM + tid + i * 256];
        s += v[i];
    }
    s = blksum(s, rb, tid);
    const float mean = s * (1.0f / DM);
    float s2 = 0.f;
#pragma unroll
    for (int i = 0; i < 3; ++i) {
        const float d = v[i] - mean;
        s2 += d * d;
    }
    s2 = blksum(s2, rb, tid);
    const float rstd = rsqrtf(s2 * (1.0f / DM) + 1e-5f);
#pragma unroll
    for (int i = 0; i < 3; ++i) {
        const int c = tid + i * 256;
        x[(size_t)row * DM + c] = gamma[c] * (v[i] - mean) * rstd + beta[c];
    }
}

extern "C" void kernel_launch(void* const* d_in, const int* in_sizes, int n_in,
                              void* d_out, int out_size, void* d_ws, size_t ws_size,
                              hipStream_t stream)
{
    const float* query = (const float*)d_in[0];
    const float* key   = (const float*)d_in[1];
    const float* value = (const float*)d_in[2];
    const int*   mask  = (const int*)d_in[3];
    const float* Wq    = (const float*)d_in[4];
    const float* Wk    = (const float*)d_in[5];
    const float* Wv    = (const float*)d_in[6];
    const float* Wo    = (const float*)d_in[7];
    const float* bo    = (const float*)d_in[8];
    const float* gamma = (const float*)d_in[9];
    const float* beta  = (const float*)d_in[10];
    const float* temp  = (const float*)d_in[11];

    float* out  = (float*)d_out;                          // [B,SQ,DM]
    float* attn = out + (size_t)B_ * SQ_ * DM;            // [B,NH,SQ,SK] fp32

    __hip_bfloat16* Qb = (__hip_bfloat16*)d_ws;           // [B,NH,SQ,HD]
    __hip_bfloat16* Kb = Qb + (size_t)B_ * NH * SQ_ * HD; // [B,NH,SK,HD]
    __hip_bfloat16* Vt = Kb + (size_t)B_ * NH * SK_ * HD; // [B,NH,HD,SK]
    // C-region: 4 weight transposes + bf16 ctx
    __hip_bfloat16* Cb  = Vt + (size_t)B_ * NH * SK_ * HD;
    __hip_bfloat16* Wqt = Cb;
    __hip_bfloat16* Wkt = Wqt + (size_t)DM * DM;
    __hip_bfloat16* Wvt = Wkt + (size_t)DM * DM;
    __hip_bfloat16* Wot = Wvt + (size_t)DM * DM;
    __hip_bfloat16* ctxb = Wot + (size_t)DM * DM;         // [B,SQ,DM] bf16
    // cast scratch (bf16 copies of q/k/v)
    __hip_bfloat16* Shq = ctxb + (size_t)B_ * SQ_ * DM;
    __hip_bfloat16* Shk = Shq + (size_t)B_ * SQ_ * DM;
    __hip_bfloat16* Shv = Shk + (size_t)B_ * SK_ * DM;

    dim3 blk(256);
    hipLaunchKernelGGL(transpose_cast4, dim3(12, 12, 4), blk, 0, stream,
                       Wq, Wk, Wv, Wo, Wqt, Wkt, Wvt, Wot);

    hipLaunchKernelGGL(cast3_bf16, dim3(15360), blk, 0, stream,
                       query, key, value, Shq, Shk, Shv);

    hipLaunchKernelGGL(gemm_qkv, dim3(960), blk, 0, stream,
                       Shq, Shk, Shv, Wqt, Wkt, Wvt, Qb, Kb, Vt);

    hipLaunchKernelGGL(attn_flash, dim3(B_ * NH * (SQ_ / QT)), blk, 0, stream,
                       Qb, Kb, Vt, mask, temp, attn, ctxb);

    hipLaunchKernelGGL(gemm_o, dim3((B_ * SQ_ / 64) * (DM / 128)), blk, 0, stream,
                       ctxb, Wot, out, bo, query);

    hipLaunchKernelGGL(ln_kernel, dim3(B_ * SQ_), blk, 0, stream, out, gamma, beta);
}